// Round 12
// baseline (647.458 us; speedup 1.0000x reference)
//
#include <hip/hip_runtime.h>
#include <hip/hip_bf16.h>
#include <math.h>

#define NN 100000
#define NE 1600000
#define NG 128
#define H 128
#define DMAX 64   // padded CSR slots/node; P(deg>64 | Poisson16) ~ 1e-17
#define NB 391    // ceil(NN/256) dst-buckets of 256 nodes
#define BCAP 5120 // bucket edge capacity (expect 4096, +16 sigma)

typedef __attribute__((ext_vector_type(8))) short short8;
typedef __attribute__((ext_vector_type(4))) float floatx4;
typedef __attribute__((ext_vector_type(4))) int intx4;       // nt-builtin-safe
typedef __attribute__((ext_vector_type(4))) unsigned uintx4; // nt-builtin-safe

// LDS agg tile: 128 rows x 136 ushorts (272 B padded stride -> <=2-way bank
// aliasing on both the gather writes and the MFMA ds_read_b128s [m136: free])
#define LROW 136

// ---------------- init: gbase=0, gsum=0, sentinel rows ---------------------
__global__ void k_init(int* __restrict__ gbase, float* __restrict__ gsum,
                       unsigned* __restrict__ rowA, unsigned* __restrict__ rowB) {
  int t = blockIdx.x * 256 + threadIdx.x;
  if (t < NB) gbase[t] = 0;
  else if (t < NB + NG * H) gsum[t - NB] = 0.f;
  else if (t < NB + NG * H + 64) rowA[t - NB - NG * H] = 0u;
  else if (t < NB + NG * H + 128) rowB[t - NB - NG * H - 64] = 0u;
}

// ---------------- two-phase CSR build ----------------
// Phase 1: LDS histogram per block -> ONE global atomicAdd per (block,bucket),
// contiguous pair-appends (write-combined). 16x fewer global atomics than the
// R5-R10 single-pass fill (which walled at ~70us).
__global__ __launch_bounds__(256) void k_bucket(const int* __restrict__ ei,
                                                int* __restrict__ gbase,
                                                int2* __restrict__ pairs) {
  __shared__ int scnt[NB];
  __shared__ int sbase[NB];
  const int tid = threadIdx.x;
  const int e0 = blockIdx.x * 6250;
  int e1 = e0 + 6250;
  if (e1 > NE) e1 = NE;
  for (int i = tid; i < NB; i += 256) scnt[i] = 0;
  __syncthreads();
  const int* dst = ei + NE;
  for (int e = e0 + tid; e < e1; e += 256) {
    int d = __builtin_nontemporal_load(dst + e);
    atomicAdd(&scnt[d >> 8], 1);
  }
  __syncthreads();
  for (int i = tid; i < NB; i += 256) {
    int c = scnt[i];
    sbase[i] = c ? atomicAdd(&gbase[i], c) : 0;
    scnt[i] = 0;
  }
  __syncthreads();
  for (int e = e0 + tid; e < e1; e += 256) {
    int d = __builtin_nontemporal_load(dst + e);
    int s = __builtin_nontemporal_load(ei + e);
    int b = d >> 8;
    int p = sbase[b] + atomicAdd(&scnt[b], 1);
    if (p < BCAP) pairs[(size_t)b * BCAP + p] = make_int2(s, d);
  }
}

// Phase 2: one block OWNS one bucket (256 dsts) -> dst counters in LDS (no
// global atomics), 64 KB colp slice single-writer, fcnt written directly.
__global__ __launch_bounds__(256) void k_fill2(const int2* __restrict__ pairs,
                                               const int* __restrict__ gbase,
                                               int* __restrict__ fcnt,
                                               int* __restrict__ colp) {
  __shared__ int scnt[256];
  const int b = blockIdx.x;
  const int d0 = b << 8;
  const int tid = threadIdx.x;
  scnt[tid] = 0;
  __syncthreads();
  int n = gbase[b];
  if (n > BCAP) n = BCAP;
  const int2* pp = pairs + (size_t)b * BCAP;
  for (int e = tid; e < n; e += 256) {
    int2 sd = pp[e];  // coalesced
    int dl = sd.y - d0;
    int pos = atomicAdd(&scnt[dl], 1);  // LDS atomic
    if (pos < DMAX) colp[((size_t)(d0 + dl) << 6) + pos] = sd.x;
  }
  __syncthreads();
  int d = d0 + tid;
  if (d < NN) {
    int c = scnt[tid];
    fcnt[d] = (c > DMAX) ? DMAX : c;
  }
}

// ---------------- bf16 helpers ----------------
__device__ inline unsigned pk_bf16(float a, float b) {  // RNE pack (lo=a, hi=b)
  unsigned ua = __float_as_uint(a), ub = __float_as_uint(b);
  ua = (ua + 0x7fffu + ((ua >> 16) & 1u)) >> 16;
  ub = (ub + 0x7fffu + ((ub >> 16) & 1u)) & 0xffff0000u;
  return ua | ub;
}

__device__ inline void acc8(float* a, uintx4 u) {  // 8 packed bf16 += into fp32
  a[0] += __uint_as_float(u.x << 16);
  a[1] += __uint_as_float(u.x & 0xffff0000u);
  a[2] += __uint_as_float(u.y << 16);
  a[3] += __uint_as_float(u.y & 0xffff0000u);
  a[4] += __uint_as_float(u.z << 16);
  a[5] += __uint_as_float(u.z & 0xffff0000u);
  a[6] += __uint_as_float(u.w << 16);
  a[7] += __uint_as_float(u.w & 0xffff0000u);
}

// ---------------- FUSED gather-aggregate + MFMA GEMM -----------------------
// R11: aggbf3 is fabric-line-rate bound (195 MB L2-miss @ 3.4 TB/s); gemm is
// MFMA-bound. Fusing (a) removes the 25+25 MB agg HBM round-trip per layer,
// (b) overlaps gather-phase blocks with MFMA-phase blocks on each CU.
// Numerics identical to split version (same fp32 sums, same RNE pack).
__global__ __launch_bounds__(256) void k_agg_gemm(
    const uintx4* __restrict__ xx,            // gather source (= X), 16B units
    const __hip_bfloat16* __restrict__ X,     // GEMM second operand rows
    const int* __restrict__ fcnt, const int* __restrict__ colp,
    const __hip_bfloat16* __restrict__ Wf, const float* __restrict__ br,
    __hip_bfloat16* __restrict__ out) {
  __shared__ unsigned short sAgg[128 * LROW];
  const int tid = threadIdx.x;
  const int nb0 = blockIdx.x * 128;

  // ---- phase A: gather-aggregate 128 rows into LDS (aggbf3 pattern) ----
  {
    const int ql = tid & 15;   // 16B chunk of row
    const int ng = tid >> 4;   // 0..15: node within group
#pragma unroll
    for (int iter = 0; iter < 8; ++iter) {
      int nl = iter * 16 + ng;
      int node = nb0 + nl;
      float a0[8] = {0}, a1[8] = {0}, a2[8] = {0}, a3[8] = {0};
      int cnt = (node < NN) ? fcnt[node] : 0;
      cnt = (cnt + 3) & ~3;
      const int* cp = colp + ((size_t)node << 6);
      for (int i = 0; i < cnt; i += 4) {
        intx4 ss = __builtin_nontemporal_load((const intx4*)(cp + i));
        uintx4 u0 = xx[(size_t)ss.x * 16 + ql];
        uintx4 u1 = xx[(size_t)ss.y * 16 + ql];
        uintx4 u2 = xx[(size_t)ss.z * 16 + ql];
        uintx4 u3 = xx[(size_t)ss.w * 16 + ql];
        acc8(a0, u0);
        acc8(a1, u1);
        acc8(a2, u2);
        acc8(a3, u3);
      }
      float s[8];
#pragma unroll
      for (int t = 0; t < 8; ++t) s[t] = (a0[t] + a1[t]) + (a2[t] + a3[t]);
      uintx4 o;
      o.x = pk_bf16(s[0], s[1]);
      o.y = pk_bf16(s[2], s[3]);
      o.z = pk_bf16(s[4], s[5]);
      o.w = pk_bf16(s[6], s[7]);
      *(uintx4*)&sAgg[nl * LROW + ql * 8] = o;
    }
  }
  __syncthreads();

  // ---- phase B: MFMA tile (A-frags for K<128 from LDS, K>=128 from X) ----
  const int wv = tid >> 6, lane = tid & 63;
  const int quad = lane >> 4, lr = lane & 15;
  const int mbase = nb0 + wv * 32;

  floatx4 acc[2][8];
#pragma unroll
  for (int rt = 0; rt < 2; ++rt)
#pragma unroll
    for (int ct = 0; ct < 8; ++ct) acc[rt][ct] = (floatx4){0.f, 0.f, 0.f, 0.f};

  int r0 = mbase + lr;      if (r0 > NN - 1) r0 = NN - 1;
  int r1 = mbase + 16 + lr; if (r1 > NN - 1) r1 = NN - 1;
  const int rl0 = wv * 32 + lr;  // local LDS rows

#pragma unroll
  for (int kt = 0; kt < 8; ++kt) {
    short8 a0, a1;
    if (kt < 4) {
      const unsigned short* ap = &sAgg[rl0 * LROW + kt * 32 + quad * 8];
      a0 = *(const short8*)ap;
      a1 = *(const short8*)(ap + 16 * LROW);
    } else {
      const size_t koff = (size_t)(kt & 3) * 32 + quad * 8;
      a0 = __builtin_nontemporal_load((const short8*)(X + (size_t)r0 * H + koff));
      a1 = __builtin_nontemporal_load((const short8*)(X + (size_t)r1 * H + koff));
    }
    const __hip_bfloat16* wb = Wf + (size_t)kt * 4096 + (size_t)lr * 32 + quad * 8;
#pragma unroll
    for (int ct = 0; ct < 8; ++ct) {
      short8 b = *(const short8*)(wb + ct * 16 * 32);
      acc[0][ct] = __builtin_amdgcn_mfma_f32_16x16x32_bf16(a0, b, acc[0][ct], 0, 0, 0);
      acc[1][ct] = __builtin_amdgcn_mfma_f32_16x16x32_bf16(a1, b, acc[1][ct], 0, 0, 0);
    }
  }

  // C/D layout: col = lane&15, row = quad*4 + reg  [m89-verified]
#pragma unroll
  for (int rt = 0; rt < 2; ++rt) {
    int row0 = mbase + rt * 16 + quad * 4;
#pragma unroll
    for (int ct = 0; ct < 8; ++ct) {
      int n = ct * 16 + lr;
      float bias = br[n];
#pragma unroll
      for (int rg = 0; rg < 4; ++rg) {
        int row = row0 + rg;
        if (row < NN) {
          float v = fmaxf(acc[rt][ct][rg] + bias, 0.f);
          out[(size_t)row * H + n] = __float2bfloat16(v);
        }
      }
    }
  }
}

// layer-1 aggregation in F_IN=4 space: 4 threads/node, exact-cnt loop.
// Also writes the <=3 sentinel slots per node (NN = zeroed row).
__global__ void k_agg4b(const float* __restrict__ x, const int* __restrict__ fcnt,
                        int* __restrict__ colp, float* __restrict__ agg4) {
  int t = blockIdx.x * blockDim.x + threadIdx.x;
  int node = t >> 2, q = t & 3;
  if (node >= NN) return;
  int cnt = fcnt[node];
  int up = (cnt + 3) & ~3;
  int pi = cnt + q;
  if (pi < up) colp[(node << 6) + pi] = NN;  // sentinel padding
  const int* cp = colp + (node << 6);
  float4 acc = make_float4(0.f, 0.f, 0.f, 0.f);
  for (int e = q; e < cnt; e += 4) {
    float4 v = ((const float4*)x)[cp[e]];
    acc.x += v.x; acc.y += v.y; acc.z += v.z; acc.w += v.w;
  }
#pragma unroll
  for (int d = 1; d < 4; d <<= 1) {
    acc.x += __shfl_xor(acc.x, d);
    acc.y += __shfl_xor(acc.y, d);
    acc.z += __shfl_xor(acc.z, d);
    acc.w += __shfl_xor(acc.w, d);
  }
  if (q == 0) ((float4*)agg4)[node] = acc;
}

// ---------------- layer-1 GEMM (K=4+4), fp32 math, bf16 output -------------
__global__ void k_gemm4(const float* __restrict__ agg4, const float* __restrict__ x4,
                        const float* __restrict__ Wr, const float* __restrict__ Wo,
                        const float* __restrict__ br, __hip_bfloat16* __restrict__ out) {
  __shared__ float sWr[512], sWo[512], sbr[128];
  int tid = threadIdx.x;
  sWr[tid] = Wr[tid]; sWr[tid + 256] = Wr[tid + 256];
  sWo[tid] = Wo[tid]; sWo[tid + 256] = Wo[tid + 256];
  if (tid < 128) sbr[tid] = br[tid];
  __syncthreads();
  int node = blockIdx.x * 2 + (tid >> 7);
  int j = tid & 127;
  if (node >= NN) return;
  float4 a = ((const float4*)agg4)[node];
  float4 xv = ((const float4*)x4)[node];
  float acc = sbr[j];
  acc = fmaf(a.x, sWr[0 * 128 + j], acc);
  acc = fmaf(a.y, sWr[1 * 128 + j], acc);
  acc = fmaf(a.z, sWr[2 * 128 + j], acc);
  acc = fmaf(a.w, sWr[3 * 128 + j], acc);
  acc = fmaf(xv.x, sWo[0 * 128 + j], acc);
  acc = fmaf(xv.y, sWo[1 * 128 + j], acc);
  acc = fmaf(xv.z, sWo[2 * 128 + j], acc);
  acc = fmaf(xv.w, sWo[3 * 128 + j], acc);
  out[(size_t)node * H + j] = __float2bfloat16(fmaxf(acc, 0.f));
}

// ---------------- W -> B-fragment-order bf16 conversion (all 3 layers) -----
__global__ void k_wcvt3(const float* __restrict__ Wr1, const float* __restrict__ Wo1,
                        const float* __restrict__ Wr2, const float* __restrict__ Wo2,
                        const float* __restrict__ Wr3, const float* __restrict__ Wo3,
                        __hip_bfloat16* __restrict__ wf) {
  int t = blockIdx.x * 256 + threadIdx.x;  // 3*32768 total
  int L = t >> 15, tt = t & 32767;
  const float* Wr = (L == 0) ? Wr1 : (L == 1) ? Wr2 : Wr3;
  const float* Wo = (L == 0) ? Wo1 : (L == 1) ? Wo2 : Wo3;
  int j = tt & 7, quad = (tt >> 3) & 3, n = (tt >> 5) & 127, kt = tt >> 12;
  int r = kt * 32 + quad * 8 + j;
  float v = (r < 128) ? Wr[r * 128 + n] : Wo[(r - 128) * 128 + n];
  wf[t] = __float2bfloat16(v);
}

// ---------------- pooling + head ----------------
#define POOL_TILE 128
__global__ void k_pool2(const __hip_bfloat16* __restrict__ x, const int* __restrict__ batch,
                        float* __restrict__ gsum) {
  int n0 = blockIdx.x * POOL_TILE;
  int j = threadIdx.x;
  int end = n0 + POOL_TILE;
  if (end > NN) end = NN;
  if (n0 >= NN) return;
  int cur_g = batch[n0];
  float acc = 0.f;
  const unsigned short* xs = (const unsigned short*)x;
  for (int i = n0; i < end; ++i) {
    int g = batch[i];  // wave-uniform load, cache-broadcast
    if (g != cur_g) {
      atomicAdd(&gsum[cur_g * H + j], acc);
      acc = 0.f;
      cur_g = g;
    }
    unsigned u = __builtin_nontemporal_load(xs + (size_t)i * H + j);
    acc += __uint_as_float(u << 16);
  }
  atomicAdd(&gsum[cur_g * H + j], acc);
}

__global__ void k_head2(const float* __restrict__ gsum, const int* __restrict__ batch,
                        const float* __restrict__ W5, const float* __restrict__ b5,
                        const float* __restrict__ W6, const float* __restrict__ b6,
                        const float* __restrict__ W7, const float* __restrict__ b7,
                        const float* __restrict__ W8, const float* __restrict__ b8,
                        const float* __restrict__ Wl, const float* __restrict__ bl,
                        float* __restrict__ out) {
  __shared__ float s0[128], s1[128];
  __shared__ int sb[2];
  const int g = blockIdx.x, j = threadIdx.x;
  if (j < 2) {  // binary search for bounds of graph g (batch sorted)
    int tgt = g + j, lo = 0, hi = NN;
    while (lo < hi) {
      int mid = (lo + hi) >> 1;
      if (batch[mid] < tgt) lo = mid + 1; else hi = mid;
    }
    sb[j] = lo;
  }
  __syncthreads();
  float cnt = (float)(sb[1] - sb[0]);
  s0[j] = gsum[g * 128 + j] / fmaxf(cnt, 1.f);
  __syncthreads();
  const float* Ws[4] = {W5, W6, W7, W8};
  const float* bs[4] = {b5, b6, b7, b8};
  float* cur = s0;
  float* nxt = s1;
  for (int L = 0; L < 4; ++L) {
    const float* W = Ws[L];
    float a = bs[L][j];
    for (int k = 0; k < 128; ++k) a = fmaf(cur[k], W[k * 128 + j], a);
    nxt[j] = fmaxf(a, 0.f);
    __syncthreads();
    float* t = cur; cur = nxt; nxt = t;
  }
  if (j < 2) {
    float a = bl[j];
    for (int k = 0; k < 128; ++k) a = fmaf(cur[k], Wl[k * 2 + j], a);
    out[g * 2 + j] = 1.f / (1.f + __expf(-a));
  }
}

// ---------------- launch ----------------
static inline char* ws_take(char*& p, size_t bytes) {
  char* r = p;
  p += (bytes + 255) & ~(size_t)255;
  return r;
}

extern "C" void kernel_launch(void* const* d_in, const int* in_sizes, int n_in,
                              void* d_out, int out_size, void* d_ws, size_t ws_size,
                              hipStream_t stream) {
  const float* x0 = (const float*)d_in[0];
  const int* ei = (const int*)d_in[1];
  const int* batch = (const int*)d_in[2];
  const float* Wr[4] = {(const float*)d_in[3], (const float*)d_in[6],
                        (const float*)d_in[9], (const float*)d_in[12]};
  const float* brr[4] = {(const float*)d_in[4], (const float*)d_in[7],
                         (const float*)d_in[10], (const float*)d_in[13]};
  const float* Wo[4] = {(const float*)d_in[5], (const float*)d_in[8],
                        (const float*)d_in[11], (const float*)d_in[14]};
  const float* W5 = (const float*)d_in[15];
  const float* b5 = (const float*)d_in[16];
  const float* W6 = (const float*)d_in[17];
  const float* b6 = (const float*)d_in[18];
  const float* W7 = (const float*)d_in[19];
  const float* b7 = (const float*)d_in[20];
  const float* W8 = (const float*)d_in[21];
  const float* b8 = (const float*)d_in[22];
  const float* Wl = (const float*)d_in[23];
  const float* bl = (const float*)d_in[24];
  float* out = (float*)d_out;

  char* p = (char*)d_ws;
  int* fcnt = (int*)ws_take(p, (size_t)NN * 4);
  int* colp = (int*)ws_take(p, (size_t)NN * DMAX * 4);
  int2* pairs = (int2*)ws_take(p, (size_t)NB * BCAP * 8);  // 16 MB
  __hip_bfloat16* bufA = (__hip_bfloat16*)ws_take(p, (size_t)(NN + 1) * H * 2);
  __hip_bfloat16* bufB = (__hip_bfloat16*)ws_take(p, (size_t)(NN + 1) * H * 2);
  float* agg4 = (float*)ws_take(p, (size_t)NN * 4 * 4);
  float* gsum = (float*)ws_take(p, (size_t)NG * H * 4);
  __hip_bfloat16* wfall = (__hip_bfloat16*)ws_take(p, 3 * 32768 * 2);
  int* gbase = (int*)ws_take(p, NB * 4);
  __hip_bfloat16* wf1 = wfall;
  __hip_bfloat16* wf2 = wfall + 32768;
  __hip_bfloat16* wf3 = wfall + 65536;
  (void)ws_size; (void)in_sizes; (void)n_in; (void)out_size;

  k_init<<<(NB + NG * H + 128 + 255) / 256, 256, 0, stream>>>(
      gbase, gsum, (unsigned*)(bufA + (size_t)NN * H), (unsigned*)(bufB + (size_t)NN * H));
  k_wcvt3<<<384, 256, 0, stream>>>(Wr[1], Wo[1], Wr[2], Wo[2], Wr[3], Wo[3], wfall);
  k_bucket<<<256, 256, 0, stream>>>(ei, gbase, pairs);
  k_fill2<<<NB, 256, 0, stream>>>(pairs, gbase, fcnt, colp);

  // layer 1 (F_IN=4): aggregate in input space (also writes sentinel pads),
  // then small GEMM -> bf16
  k_agg4b<<<(NN * 4 + 255) / 256, 256, 0, stream>>>(x0, fcnt, colp, agg4);
  k_gemm4<<<NN / 2, 256, 0, stream>>>(agg4, x0, Wr[0], Wo[0], brr[0], bufA);

  // layers 2-4: fused gather-agg + MFMA GEMM (no agg round-trip)
  k_agg_gemm<<<782, 256, 0, stream>>>((const uintx4*)bufA, bufA, fcnt, colp, wf1, brr[1], bufB);
  k_agg_gemm<<<782, 256, 0, stream>>>((const uintx4*)bufB, bufB, fcnt, colp, wf2, brr[2], bufA);
  k_agg_gemm<<<782, 256, 0, stream>>>((const uintx4*)bufA, bufA, fcnt, colp, wf3, brr[3], bufB);

  // mean pool + MLP head + sigmoid
  k_pool2<<<(NN + POOL_TILE - 1) / POOL_TILE, 128, 0, stream>>>(bufB, batch, gsum);
  k_head2<<<NG, 128, 0, stream>>>(gsum, batch, W5, b5, W6, b6, W7, b7, W8, b8, Wl, bl, out);
}

// Round 13
// 595.212 us; speedup vs baseline: 1.0878x; 1.0878x over previous
//
#include <hip/hip_runtime.h>
#include <hip/hip_bf16.h>
#include <math.h>

#define NN 100000
#define NE 1600000
#define NG 128
#define H 128
#define DMAX 64   // padded CSR slots/node; P(deg>64 | Poisson16) ~ 1e-17
#define NB 782    // ceil(NN/128) dst-buckets of 128 nodes (R13: was 256/391)
#define BCAP 2816 // bucket edge capacity (mean 2048, +17 sigma)

typedef __attribute__((ext_vector_type(8))) short short8;
typedef __attribute__((ext_vector_type(4))) float floatx4;
typedef __attribute__((ext_vector_type(4))) int intx4;       // nt-builtin-safe
typedef __attribute__((ext_vector_type(4))) unsigned uintx4; // nt-builtin-safe

// ---------------- init: gbase=0, gsum=0, sentinel rows ---------------------
__global__ void k_init(int* __restrict__ gbase, float* __restrict__ gsum,
                       unsigned* __restrict__ rowA, unsigned* __restrict__ rowB) {
  int t = blockIdx.x * 256 + threadIdx.x;
  if (t < NB) gbase[t] = 0;
  else if (t < NB + NG * H) gsum[t - NB] = 0.f;
  else if (t < NB + NG * H + 64) rowA[t - NB - NG * H] = 0u;
  else if (t < NB + NG * H + 128) rowB[t - NB - NG * H - 64] = 0u;
}

// ---------------- two-phase CSR build ----------------
// R12 lesson: do NOT fuse latency-bound gather into compute kernels (fusion
// cost 8x longer per-thread chains at 20% occupancy -> +45 us). Split design
// restored. R13: 128-dst buckets double phase-2 parallelism (391->782 blocks).
__global__ __launch_bounds__(256) void k_bucket(const int* __restrict__ ei,
                                                int* __restrict__ gbase,
                                                int2* __restrict__ pairs) {
  __shared__ int scnt[NB];
  __shared__ int sbase[NB];
  const int tid = threadIdx.x;
  const int e0 = blockIdx.x * 3125;
  int e1 = e0 + 3125;
  if (e1 > NE) e1 = NE;
  for (int i = tid; i < NB; i += 256) scnt[i] = 0;
  __syncthreads();
  const int* dst = ei + NE;
  for (int e = e0 + tid; e < e1; e += 256) {
    int d = __builtin_nontemporal_load(dst + e);
    atomicAdd(&scnt[d >> 7], 1);
  }
  __syncthreads();
  for (int i = tid; i < NB; i += 256) {
    int c = scnt[i];
    sbase[i] = c ? atomicAdd(&gbase[i], c) : 0;
    scnt[i] = 0;
  }
  __syncthreads();
  for (int e = e0 + tid; e < e1; e += 256) {
    int d = __builtin_nontemporal_load(dst + e);
    int s = __builtin_nontemporal_load(ei + e);
    int b = d >> 7;
    int p = sbase[b] + atomicAdd(&scnt[b], 1);
    if (p < BCAP) pairs[(size_t)b * BCAP + p] = make_int2(s, d);
  }
}

// Phase 2: one block OWNS one 128-dst bucket -> counters in LDS (no global
// atomics), 32 KB colp slice single-writer, fcnt written directly.
__global__ __launch_bounds__(256) void k_fill2(const int2* __restrict__ pairs,
                                               const int* __restrict__ gbase,
                                               int* __restrict__ fcnt,
                                               int* __restrict__ colp) {
  __shared__ int scnt[128];
  const int b = blockIdx.x;
  const int d0 = b << 7;
  const int tid = threadIdx.x;
  if (tid < 128) scnt[tid] = 0;
  __syncthreads();
  int n = gbase[b];
  if (n > BCAP) n = BCAP;
  const int2* pp = pairs + (size_t)b * BCAP;
  for (int e = tid; e < n; e += 256) {
    int2 sd = pp[e];  // coalesced
    int dl = sd.y - d0;
    int pos = atomicAdd(&scnt[dl], 1);  // LDS atomic
    if (pos < DMAX) colp[((size_t)(d0 + dl) << 6) + pos] = sd.x;
  }
  __syncthreads();
  int d = d0 + tid;
  if (tid < 128 && d < NN) {
    int c = scnt[tid];
    fcnt[d] = (c > DMAX) ? DMAX : c;
  }
}

// ---------------- bf16 helpers ----------------
__device__ inline unsigned pk_bf16(float a, float b) {  // RNE pack (lo=a, hi=b)
  unsigned ua = __float_as_uint(a), ub = __float_as_uint(b);
  ua = (ua + 0x7fffu + ((ua >> 16) & 1u)) >> 16;
  ub = (ub + 0x7fffu + ((ub >> 16) & 1u)) & 0xffff0000u;
  return ua | ub;
}

__device__ inline void acc8(float* a, uintx4 u) {  // 8 packed bf16 += into fp32
  a[0] += __uint_as_float(u.x << 16);
  a[1] += __uint_as_float(u.x & 0xffff0000u);
  a[2] += __uint_as_float(u.y << 16);
  a[3] += __uint_as_float(u.y & 0xffff0000u);
  a[4] += __uint_as_float(u.z << 16);
  a[5] += __uint_as_float(u.z & 0xffff0000u);
  a[6] += __uint_as_float(u.w << 16);
  a[7] += __uint_as_float(u.w & 0xffff0000u);
}

// ---------------- aggregation (bf16 x, fp32 accumulate, bf16 agg) ----------
// 16 B/lane (uintx4, stride 16 per 256 B row), 4 nodes/wave, depth-4,
// tail-free via sentinel row NN. Fabric-line-rate bound (195 MB L2-miss @
// ~3.4 TB/s; depth/instr-count/fusion experiments R6/R8/R12 all confirm).
__global__ void k_aggbf3(const uintx4* __restrict__ xx, const int* __restrict__ fcnt,
                         const int* __restrict__ colp, uintx4* __restrict__ agg) {
  int w = (blockIdx.x * blockDim.x + threadIdx.x) >> 6;
  int lane = threadIdx.x & 63;
  int qr = lane >> 4, ql = lane & 15;  // qr: node-of-wave, ql: 16B chunk of row
  int node = 4 * w + qr;
  if (node >= NN) return;
  int cnt = fcnt[node];
  cnt = (cnt + 3) & ~3;
  const int* cp = colp + (node << 6);
  float a0[8] = {0}, a1[8] = {0}, a2[8] = {0}, a3[8] = {0};
  for (int i = 0; i < cnt; i += 4) {
    intx4 ss = __builtin_nontemporal_load((const intx4*)(cp + i));
    uintx4 u0 = xx[(size_t)ss.x * 16 + ql];
    uintx4 u1 = xx[(size_t)ss.y * 16 + ql];
    uintx4 u2 = xx[(size_t)ss.z * 16 + ql];
    uintx4 u3 = xx[(size_t)ss.w * 16 + ql];
    acc8(a0, u0);
    acc8(a1, u1);
    acc8(a2, u2);
    acc8(a3, u3);
  }
  float s[8];
#pragma unroll
  for (int t = 0; t < 8; ++t) s[t] = (a0[t] + a1[t]) + (a2[t] + a3[t]);
  uintx4 o;
  o.x = pk_bf16(s[0], s[1]);
  o.y = pk_bf16(s[2], s[3]);
  o.z = pk_bf16(s[4], s[5]);
  o.w = pk_bf16(s[6], s[7]);
  __builtin_nontemporal_store(o, agg + (size_t)node * 16 + ql);
}

// layer-1 aggregation in F_IN=4 space: 4 threads/node, exact-cnt loop.
// Also writes the <=3 sentinel slots per node (NN = zeroed row).
__global__ void k_agg4b(const float* __restrict__ x, const int* __restrict__ fcnt,
                        int* __restrict__ colp, float* __restrict__ agg4) {
  int t = blockIdx.x * blockDim.x + threadIdx.x;
  int node = t >> 2, q = t & 3;
  if (node >= NN) return;
  int cnt = fcnt[node];
  int up = (cnt + 3) & ~3;
  int pi = cnt + q;
  if (pi < up) colp[(node << 6) + pi] = NN;  // sentinel padding
  const int* cp = colp + (node << 6);
  float4 acc = make_float4(0.f, 0.f, 0.f, 0.f);
  for (int e = q; e < cnt; e += 4) {
    float4 v = ((const float4*)x)[cp[e]];
    acc.x += v.x; acc.y += v.y; acc.z += v.z; acc.w += v.w;
  }
#pragma unroll
  for (int d = 1; d < 4; d <<= 1) {
    acc.x += __shfl_xor(acc.x, d);
    acc.y += __shfl_xor(acc.y, d);
    acc.z += __shfl_xor(acc.z, d);
    acc.w += __shfl_xor(acc.w, d);
  }
  if (q == 0) ((float4*)agg4)[node] = acc;
}

// ---------------- layer-1 GEMM (K=4+4), fp32 math, bf16 output -------------
__global__ void k_gemm4(const float* __restrict__ agg4, const float* __restrict__ x4,
                        const float* __restrict__ Wr, const float* __restrict__ Wo,
                        const float* __restrict__ br, __hip_bfloat16* __restrict__ out) {
  __shared__ float sWr[512], sWo[512], sbr[128];
  int tid = threadIdx.x;
  sWr[tid] = Wr[tid]; sWr[tid + 256] = Wr[tid + 256];
  sWo[tid] = Wo[tid]; sWo[tid + 256] = Wo[tid + 256];
  if (tid < 128) sbr[tid] = br[tid];
  __syncthreads();
  int node = blockIdx.x * 2 + (tid >> 7);
  int j = tid & 127;
  if (node >= NN) return;
  float4 a = ((const float4*)agg4)[node];
  float4 xv = ((const float4*)x4)[node];
  float acc = sbr[j];
  acc = fmaf(a.x, sWr[0 * 128 + j], acc);
  acc = fmaf(a.y, sWr[1 * 128 + j], acc);
  acc = fmaf(a.z, sWr[2 * 128 + j], acc);
  acc = fmaf(a.w, sWr[3 * 128 + j], acc);
  acc = fmaf(xv.x, sWo[0 * 128 + j], acc);
  acc = fmaf(xv.y, sWo[1 * 128 + j], acc);
  acc = fmaf(xv.z, sWo[2 * 128 + j], acc);
  acc = fmaf(xv.w, sWo[3 * 128 + j], acc);
  out[(size_t)node * H + j] = __float2bfloat16(fmaxf(acc, 0.f));
}

// ---------------- W -> B-fragment-order bf16 conversion (all 3 layers) -----
__global__ void k_wcvt3(const float* __restrict__ Wr1, const float* __restrict__ Wo1,
                        const float* __restrict__ Wr2, const float* __restrict__ Wo2,
                        const float* __restrict__ Wr3, const float* __restrict__ Wo3,
                        __hip_bfloat16* __restrict__ wf) {
  int t = blockIdx.x * 256 + threadIdx.x;  // 3*32768 total
  int L = t >> 15, tt = t & 32767;
  const float* Wr = (L == 0) ? Wr1 : (L == 1) ? Wr2 : Wr3;
  const float* Wo = (L == 0) ? Wo1 : (L == 1) ? Wo2 : Wo3;
  int j = tt & 7, quad = (tt >> 3) & 3, n = (tt >> 5) & 127, kt = tt >> 12;
  int r = kt * 32 + quad * 8 + j;
  float v = (r < 128) ? Wr[r * 128 + n] : Wo[(r - 128) * 128 + n];
  wf[t] = __float2bfloat16(v);
}

// ---------------- MFMA GEMM: relu([agg|x] @ [Wr;Wo] + br) ------------------
__global__ __launch_bounds__(256) void k_gemm_mfma(
    const __hip_bfloat16* __restrict__ A, const __hip_bfloat16* __restrict__ X,
    const __hip_bfloat16* __restrict__ Wf, const float* __restrict__ br,
    __hip_bfloat16* __restrict__ out) {
  const int tid = threadIdx.x;
  const int wv = tid >> 6, lane = tid & 63;
  const int quad = lane >> 4, lr = lane & 15;
  const int mbase = blockIdx.x * 128 + wv * 32;

  floatx4 acc[2][8];
#pragma unroll
  for (int rt = 0; rt < 2; ++rt)
#pragma unroll
    for (int ct = 0; ct < 8; ++ct) acc[rt][ct] = (floatx4){0.f, 0.f, 0.f, 0.f};

  int r0 = mbase + lr;      if (r0 > NN - 1) r0 = NN - 1;
  int r1 = mbase + 16 + lr; if (r1 > NN - 1) r1 = NN - 1;

#pragma unroll
  for (int kt = 0; kt < 8; ++kt) {
    const __hip_bfloat16* base = (kt < 4) ? A : X;
    const size_t koff = (size_t)(kt & 3) * 32 + quad * 8;
    short8 a0 = __builtin_nontemporal_load((const short8*)(base + (size_t)r0 * H + koff));
    short8 a1 = __builtin_nontemporal_load((const short8*)(base + (size_t)r1 * H + koff));
    const __hip_bfloat16* wb = Wf + (size_t)kt * 4096 + (size_t)lr * 32 + quad * 8;
#pragma unroll
    for (int ct = 0; ct < 8; ++ct) {
      short8 b = *(const short8*)(wb + ct * 16 * 32);
      acc[0][ct] = __builtin_amdgcn_mfma_f32_16x16x32_bf16(a0, b, acc[0][ct], 0, 0, 0);
      acc[1][ct] = __builtin_amdgcn_mfma_f32_16x16x32_bf16(a1, b, acc[1][ct], 0, 0, 0);
    }
  }

  // C/D layout: col = lane&15, row = quad*4 + reg  [m89-verified]
#pragma unroll
  for (int rt = 0; rt < 2; ++rt) {
    int row0 = mbase + rt * 16 + quad * 4;
#pragma unroll
    for (int ct = 0; ct < 8; ++ct) {
      int n = ct * 16 + lr;
      float bias = br[n];
#pragma unroll
      for (int rg = 0; rg < 4; ++rg) {
        int row = row0 + rg;
        if (row < NN) {
          float v = fmaxf(acc[rt][ct][rg] + bias, 0.f);
          out[(size_t)row * H + n] = __float2bfloat16(v);
        }
      }
    }
  }
}

// ---------------- pooling + head ----------------
#define POOL_TILE 128
__global__ void k_pool2(const __hip_bfloat16* __restrict__ x, const int* __restrict__ batch,
                        float* __restrict__ gsum) {
  int n0 = blockIdx.x * POOL_TILE;
  int j = threadIdx.x;
  int end = n0 + POOL_TILE;
  if (end > NN) end = NN;
  if (n0 >= NN) return;
  int cur_g = batch[n0];
  float acc = 0.f;
  const unsigned short* xs = (const unsigned short*)x;
  for (int i = n0; i < end; ++i) {
    int g = batch[i];  // wave-uniform load, cache-broadcast
    if (g != cur_g) {
      atomicAdd(&gsum[cur_g * H + j], acc);
      acc = 0.f;
      cur_g = g;
    }
    unsigned u = __builtin_nontemporal_load(xs + (size_t)i * H + j);
    acc += __uint_as_float(u << 16);
  }
  atomicAdd(&gsum[cur_g * H + j], acc);
}

__global__ void k_head2(const float* __restrict__ gsum, const int* __restrict__ batch,
                        const float* __restrict__ W5, const float* __restrict__ b5,
                        const float* __restrict__ W6, const float* __restrict__ b6,
                        const float* __restrict__ W7, const float* __restrict__ b7,
                        const float* __restrict__ W8, const float* __restrict__ b8,
                        const float* __restrict__ Wl, const float* __restrict__ bl,
                        float* __restrict__ out) {
  __shared__ float s0[128], s1[128];
  __shared__ int sb[2];
  const int g = blockIdx.x, j = threadIdx.x;
  if (j < 2) {  // binary search for bounds of graph g (batch sorted)
    int tgt = g + j, lo = 0, hi = NN;
    while (lo < hi) {
      int mid = (lo + hi) >> 1;
      if (batch[mid] < tgt) lo = mid + 1; else hi = mid;
    }
    sb[j] = lo;
  }
  __syncthreads();
  float cnt = (float)(sb[1] - sb[0]);
  s0[j] = gsum[g * 128 + j] / fmaxf(cnt, 1.f);
  __syncthreads();
  const float* Ws[4] = {W5, W6, W7, W8};
  const float* bs[4] = {b5, b6, b7, b8};
  float* cur = s0;
  float* nxt = s1;
  for (int L = 0; L < 4; ++L) {
    const float* W = Ws[L];
    float a = bs[L][j];
    for (int k = 0; k < 128; ++k) a = fmaf(cur[k], W[k * 128 + j], a);
    nxt[j] = fmaxf(a, 0.f);
    __syncthreads();
    float* t = cur; cur = nxt; nxt = t;
  }
  if (j < 2) {
    float a = bl[j];
    for (int k = 0; k < 128; ++k) a = fmaf(cur[k], Wl[k * 2 + j], a);
    out[g * 2 + j] = 1.f / (1.f + __expf(-a));
  }
}

// ---------------- launch ----------------
static inline char* ws_take(char*& p, size_t bytes) {
  char* r = p;
  p += (bytes + 255) & ~(size_t)255;
  return r;
}

extern "C" void kernel_launch(void* const* d_in, const int* in_sizes, int n_in,
                              void* d_out, int out_size, void* d_ws, size_t ws_size,
                              hipStream_t stream) {
  const float* x0 = (const float*)d_in[0];
  const int* ei = (const int*)d_in[1];
  const int* batch = (const int*)d_in[2];
  const float* Wr[4] = {(const float*)d_in[3], (const float*)d_in[6],
                        (const float*)d_in[9], (const float*)d_in[12]};
  const float* brr[4] = {(const float*)d_in[4], (const float*)d_in[7],
                         (const float*)d_in[10], (const float*)d_in[13]};
  const float* Wo[4] = {(const float*)d_in[5], (const float*)d_in[8],
                        (const float*)d_in[11], (const float*)d_in[14]};
  const float* W5 = (const float*)d_in[15];
  const float* b5 = (const float*)d_in[16];
  const float* W6 = (const float*)d_in[17];
  const float* b6 = (const float*)d_in[18];
  const float* W7 = (const float*)d_in[19];
  const float* b7 = (const float*)d_in[20];
  const float* W8 = (const float*)d_in[21];
  const float* b8 = (const float*)d_in[22];
  const float* Wl = (const float*)d_in[23];
  const float* bl = (const float*)d_in[24];
  float* out = (float*)d_out;

  char* p = (char*)d_ws;
  int* fcnt = (int*)ws_take(p, (size_t)NN * 4);
  int* colp = (int*)ws_take(p, (size_t)NN * DMAX * 4);
  __hip_bfloat16* agg = (__hip_bfloat16*)ws_take(p, (size_t)NN * H * 2);
  __hip_bfloat16* bufA = (__hip_bfloat16*)ws_take(p, (size_t)(NN + 1) * H * 2);
  __hip_bfloat16* bufB = (__hip_bfloat16*)ws_take(p, (size_t)(NN + 1) * H * 2);
  float* agg4 = (float*)ws_take(p, (size_t)NN * 4 * 4);
  float* gsum = (float*)ws_take(p, (size_t)NG * H * 4);
  __hip_bfloat16* wfall = (__hip_bfloat16*)ws_take(p, 3 * 32768 * 2);
  int* gbase = (int*)ws_take(p, NB * 4);
  __hip_bfloat16* wf1 = wfall;
  __hip_bfloat16* wf2 = wfall + 32768;
  __hip_bfloat16* wf3 = wfall + 65536;
  // pairs buffer (17.6 MB) aliases agg (25.6 MB): CSR build finishes before
  // the first aggbf3 write to agg.
  int2* pairs = (int2*)agg;
  (void)ws_size; (void)in_sizes; (void)n_in; (void)out_size;

  k_init<<<(NB + NG * H + 128 + 255) / 256, 256, 0, stream>>>(
      gbase, gsum, (unsigned*)(bufA + (size_t)NN * H), (unsigned*)(bufB + (size_t)NN * H));
  k_wcvt3<<<384, 256, 0, stream>>>(Wr[1], Wo[1], Wr[2], Wo[2], Wr[3], Wo[3], wfall);
  k_bucket<<<512, 256, 0, stream>>>(ei, gbase, pairs);
  k_fill2<<<NB, 256, 0, stream>>>(pairs, gbase, fcnt, colp);

  // layer 1 (F_IN=4): aggregate in input space (also writes sentinel pads),
  // then small GEMM -> bf16
  k_agg4b<<<(NN * 4 + 255) / 256, 256, 0, stream>>>(x0, fcnt, colp, agg4);
  k_gemm4<<<NN / 2, 256, 0, stream>>>(agg4, x0, Wr[0], Wo[0], brr[0], bufA);

  // layers 2-4: bf16 gather-agg + MFMA GEMM (split: R12 fusion regressed)
  k_aggbf3<<<6250, 256, 0, stream>>>((const uintx4*)bufA, fcnt, colp, (uintx4*)agg);
  k_gemm_mfma<<<782, 256, 0, stream>>>(agg, bufA, wf1, brr[1], bufB);
  k_aggbf3<<<6250, 256, 0, stream>>>((const uintx4*)bufB, fcnt, colp, (uintx4*)agg);
  k_gemm_mfma<<<782, 256, 0, stream>>>(agg, bufB, wf2, brr[2], bufA);
  k_aggbf3<<<6250, 256, 0, stream>>>((const uintx4*)bufA, fcnt, colp, (uintx4*)agg);
  k_gemm_mfma<<<782, 256, 0, stream>>>(agg, bufA, wf3, brr[3], bufB);

  // mean pool + MLP head + sigmoid
  k_pool2<<<(NN + POOL_TILE - 1) / POOL_TILE, 128, 0, stream>>>(bufB, batch, gsum);
  k_head2<<<NG, 128, 0, stream>>>(gsum, batch, W5, b5, W6, b6, W7, b7, W8, b8, Wl, bl, out);
}

// Round 14
// 571.339 us; speedup vs baseline: 1.1332x; 1.0418x over previous
//
#include <hip/hip_runtime.h>
#include <hip/hip_bf16.h>
#include <math.h>

#define NN 100000
#define NE 1600000
#define NG 128
#define H 128
#define DMAX 64   // padded CSR slots/node; P(deg>64 | Poisson16) ~ 1e-17
#define NB 391    // dst-buckets of 256 nodes
#define BCAP 5120 // bucket edge capacity (mean 4092, +16 sigma)
#define EPB 3125  // edges per bucket-build block (512 blocks x 3125 = NE)

typedef __attribute__((ext_vector_type(8))) short short8;
typedef __attribute__((ext_vector_type(4))) float floatx4;
typedef __attribute__((ext_vector_type(4))) int intx4;       // nt-builtin-safe
typedef __attribute__((ext_vector_type(4))) unsigned uintx4; // nt-builtin-safe

// ---------------- init (gbase/gsum/sentinel rows) + W conversion, fused ----
// wf[L][t], t = kt*4096 + n*32 + quad*8 + j holds W'[kt*32+quad*8+j][n]
__global__ void k_init_wcvt(int* __restrict__ gbase, float* __restrict__ gsum,
                            unsigned* __restrict__ rowA, unsigned* __restrict__ rowB,
                            const float* __restrict__ Wr1, const float* __restrict__ Wo1,
                            const float* __restrict__ Wr2, const float* __restrict__ Wo2,
                            const float* __restrict__ Wr3, const float* __restrict__ Wo3,
                            __hip_bfloat16* __restrict__ wf) {
  if (blockIdx.x < 384) {  // W conversion: 3*32768 elements
    int t = blockIdx.x * 256 + threadIdx.x;
    int L = t >> 15, tt = t & 32767;
    const float* Wr = (L == 0) ? Wr1 : (L == 1) ? Wr2 : Wr3;
    const float* Wo = (L == 0) ? Wo1 : (L == 1) ? Wo2 : Wo3;
    int j = tt & 7, quad = (tt >> 3) & 3, n = (tt >> 5) & 127, kt = tt >> 12;
    int r = kt * 32 + quad * 8 + j;
    float v = (r < 128) ? Wr[r * 128 + n] : Wo[(r - 128) * 128 + n];
    wf[t] = __float2bfloat16(v);
  } else {  // init
    int t = (blockIdx.x - 384) * 256 + threadIdx.x;
    if (t < NB) gbase[t] = 0;
    else if (t < NB + NG * H) gsum[t - NB] = 0.f;
    else if (t < NB + NG * H + 64) rowA[t - NB - NG * H] = 0u;
    else if (t < NB + NG * H + 128) rowB[t - NB - NG * H - 64] = 0u;
  }
}

// ---------------- two-phase CSR build ----------------
// R14: LDS counting-sort so pair-appends are coalesced bursts (~64 B per
// (block,bucket) group) instead of 8 B random scatter (R3-style partial-line
// amplification). One global atomicAdd per (block,bucket).
__global__ __launch_bounds__(256) void k_bucket(const int* __restrict__ ei,
                                                int* __restrict__ gbase,
                                                int2* __restrict__ pairs) {
  __shared__ int scnt[512];   // histogram, padded for scan; reused as fill ctr
  __shared__ int soff[NB];    // local exclusive offsets
  __shared__ int sbase[NB];   // global reserved base
  __shared__ int2 stg[EPB];   // bucket-sorted staging (25 KB)
  __shared__ short sbkt[EPB]; // bucket id per staged edge
  const int tid = threadIdx.x;
  const int e0 = blockIdx.x * EPB;
  const int* dst = ei + NE;

  scnt[tid] = 0;
  scnt[tid + 256] = 0;
  __syncthreads();
  for (int e = e0 + tid; e < e0 + EPB; e += 256) {
    int d = __builtin_nontemporal_load(dst + e);
    atomicAdd(&scnt[d >> 8], 1);
  }
  __syncthreads();
  int c0 = scnt[tid], c1 = scnt[tid + 256];
  // inclusive Hillis-Steele scan over 512 entries (256 threads x 2)
  for (int off = 1; off < 512; off <<= 1) {
    int v0 = (tid >= off) ? scnt[tid - off] : 0;
    int v1 = (tid + 256 >= off) ? scnt[tid + 256 - off] : 0;
    __syncthreads();
    scnt[tid] += v0;
    scnt[tid + 256] += v1;
    __syncthreads();
  }
  if (tid < NB) {
    soff[tid] = scnt[tid] - c0;
    sbase[tid] = c0 ? atomicAdd(&gbase[tid], c0) : 0;
  }
  if (tid + 256 < NB) {
    soff[tid + 256] = scnt[tid + 256] - c1;
    sbase[tid + 256] = c1 ? atomicAdd(&gbase[tid + 256], c1) : 0;
  }
  __syncthreads();
  scnt[tid] = 0;
  scnt[tid + 256] = 0;
  __syncthreads();
  for (int e = e0 + tid; e < e0 + EPB; e += 256) {
    int d = __builtin_nontemporal_load(dst + e);
    int s = __builtin_nontemporal_load(ei + e);
    int b = d >> 8;
    int p = soff[b] + atomicAdd(&scnt[b], 1);
    stg[p] = make_int2(s, d);
    sbkt[p] = (short)b;
  }
  __syncthreads();
  for (int i = tid; i < EPB; i += 256) {
    int b = sbkt[i];
    int gpos = sbase[b] + (i - soff[b]);
    if (gpos < BCAP) pairs[(size_t)b * BCAP + gpos] = stg[i];  // coalesced runs
  }
}

// Phase 2: one block OWNS one 256-dst bucket -> counters in LDS (no global
// atomics), colp slice single-writer, fcnt written directly.
__global__ __launch_bounds__(256) void k_fill2(const int2* __restrict__ pairs,
                                               const int* __restrict__ gbase,
                                               int* __restrict__ fcnt,
                                               int* __restrict__ colp) {
  __shared__ int scnt[256];
  const int b = blockIdx.x;
  const int d0 = b << 8;
  const int tid = threadIdx.x;
  scnt[tid] = 0;
  __syncthreads();
  int n = gbase[b];
  if (n > BCAP) n = BCAP;
  const int2* pp = pairs + (size_t)b * BCAP;
  for (int e = tid; e < n; e += 256) {
    int2 sd = pp[e];  // coalesced
    int dl = sd.y - d0;
    int pos = atomicAdd(&scnt[dl], 1);  // LDS atomic
    if (pos < DMAX) colp[((size_t)(d0 + dl) << 6) + pos] = sd.x;
  }
  __syncthreads();
  int d = d0 + tid;
  if (d < NN) {
    int c = scnt[tid];
    fcnt[d] = (c > DMAX) ? DMAX : c;
  }
}

// ---------------- bf16 helpers ----------------
__device__ inline unsigned pk_bf16(float a, float b) {  // RNE pack (lo=a, hi=b)
  unsigned ua = __float_as_uint(a), ub = __float_as_uint(b);
  ua = (ua + 0x7fffu + ((ua >> 16) & 1u)) >> 16;
  ub = (ub + 0x7fffu + ((ub >> 16) & 1u)) & 0xffff0000u;
  return ua | ub;
}

__device__ inline void acc8(float* a, uintx4 u) {  // 8 packed bf16 += into fp32
  a[0] += __uint_as_float(u.x << 16);
  a[1] += __uint_as_float(u.x & 0xffff0000u);
  a[2] += __uint_as_float(u.y << 16);
  a[3] += __uint_as_float(u.y & 0xffff0000u);
  a[4] += __uint_as_float(u.z << 16);
  a[5] += __uint_as_float(u.z & 0xffff0000u);
  a[6] += __uint_as_float(u.w << 16);
  a[7] += __uint_as_float(u.w & 0xffff0000u);
}

// ---------------- aggregation (bf16 x, fp32 accumulate, bf16 agg) ----------
// Fabric-line-rate bound (195 MB L2-miss @ ~3.5 TB/s; R6/R8/R12 confirm).
__global__ void k_aggbf3(const uintx4* __restrict__ xx, const int* __restrict__ fcnt,
                         const int* __restrict__ colp, uintx4* __restrict__ agg) {
  int w = (blockIdx.x * blockDim.x + threadIdx.x) >> 6;
  int lane = threadIdx.x & 63;
  int qr = lane >> 4, ql = lane & 15;  // qr: node-of-wave, ql: 16B chunk of row
  int node = 4 * w + qr;
  if (node >= NN) return;
  int cnt = fcnt[node];
  cnt = (cnt + 3) & ~3;
  const int* cp = colp + (node << 6);
  float a0[8] = {0}, a1[8] = {0}, a2[8] = {0}, a3[8] = {0};
  for (int i = 0; i < cnt; i += 4) {
    intx4 ss = __builtin_nontemporal_load((const intx4*)(cp + i));
    uintx4 u0 = xx[(size_t)ss.x * 16 + ql];
    uintx4 u1 = xx[(size_t)ss.y * 16 + ql];
    uintx4 u2 = xx[(size_t)ss.z * 16 + ql];
    uintx4 u3 = xx[(size_t)ss.w * 16 + ql];
    acc8(a0, u0);
    acc8(a1, u1);
    acc8(a2, u2);
    acc8(a3, u3);
  }
  float s[8];
#pragma unroll
  for (int t = 0; t < 8; ++t) s[t] = (a0[t] + a1[t]) + (a2[t] + a3[t]);
  uintx4 o;
  o.x = pk_bf16(s[0], s[1]);
  o.y = pk_bf16(s[2], s[3]);
  o.z = pk_bf16(s[4], s[5]);
  o.w = pk_bf16(s[6], s[7]);
  __builtin_nontemporal_store(o, agg + (size_t)node * 16 + ql);
}

// layer-1 aggregation in F_IN=4 space: 4 threads/node, exact-cnt loop.
// Also writes the <=3 sentinel slots per node (NN = zeroed row).
__global__ void k_agg4b(const float* __restrict__ x, const int* __restrict__ fcnt,
                        int* __restrict__ colp, float* __restrict__ agg4) {
  int t = blockIdx.x * blockDim.x + threadIdx.x;
  int node = t >> 2, q = t & 3;
  if (node >= NN) return;
  int cnt = fcnt[node];
  int up = (cnt + 3) & ~3;
  int pi = cnt + q;
  if (pi < up) colp[(node << 6) + pi] = NN;  // sentinel padding
  const int* cp = colp + (node << 6);
  float4 acc = make_float4(0.f, 0.f, 0.f, 0.f);
  for (int e = q; e < cnt; e += 4) {
    float4 v = ((const float4*)x)[cp[e]];
    acc.x += v.x; acc.y += v.y; acc.z += v.z; acc.w += v.w;
  }
#pragma unroll
  for (int d = 1; d < 4; d <<= 1) {
    acc.x += __shfl_xor(acc.x, d);
    acc.y += __shfl_xor(acc.y, d);
    acc.z += __shfl_xor(acc.z, d);
    acc.w += __shfl_xor(acc.w, d);
  }
  if (q == 0) ((float4*)agg4)[node] = acc;
}

// ---------------- layer-1 GEMM (K=4+4), fp32 math, bf16 output -------------
__global__ void k_gemm4(const float* __restrict__ agg4, const float* __restrict__ x4,
                        const float* __restrict__ Wr, const float* __restrict__ Wo,
                        const float* __restrict__ br, __hip_bfloat16* __restrict__ out) {
  __shared__ float sWr[512], sWo[512], sbr[128];
  int tid = threadIdx.x;
  sWr[tid] = Wr[tid]; sWr[tid + 256] = Wr[tid + 256];
  sWo[tid] = Wo[tid]; sWo[tid + 256] = Wo[tid + 256];
  if (tid < 128) sbr[tid] = br[tid];
  __syncthreads();
  int node = blockIdx.x * 2 + (tid >> 7);
  int j = tid & 127;
  if (node >= NN) return;
  float4 a = ((const float4*)agg4)[node];
  float4 xv = ((const float4*)x4)[node];
  float acc = sbr[j];
  acc = fmaf(a.x, sWr[0 * 128 + j], acc);
  acc = fmaf(a.y, sWr[1 * 128 + j], acc);
  acc = fmaf(a.z, sWr[2 * 128 + j], acc);
  acc = fmaf(a.w, sWr[3 * 128 + j], acc);
  acc = fmaf(xv.x, sWo[0 * 128 + j], acc);
  acc = fmaf(xv.y, sWo[1 * 128 + j], acc);
  acc = fmaf(xv.z, sWo[2 * 128 + j], acc);
  acc = fmaf(xv.w, sWo[3 * 128 + j], acc);
  out[(size_t)node * H + j] = __float2bfloat16(fmaxf(acc, 0.f));
}

// ---------------- MFMA GEMM: relu([agg|x] @ [Wr;Wo] + br) ------------------
__global__ __launch_bounds__(256) void k_gemm_mfma(
    const __hip_bfloat16* __restrict__ A, const __hip_bfloat16* __restrict__ X,
    const __hip_bfloat16* __restrict__ Wf, const float* __restrict__ br,
    __hip_bfloat16* __restrict__ out) {
  const int tid = threadIdx.x;
  const int wv = tid >> 6, lane = tid & 63;
  const int quad = lane >> 4, lr = lane & 15;
  const int mbase = blockIdx.x * 128 + wv * 32;

  floatx4 acc[2][8];
#pragma unroll
  for (int rt = 0; rt < 2; ++rt)
#pragma unroll
    for (int ct = 0; ct < 8; ++ct) acc[rt][ct] = (floatx4){0.f, 0.f, 0.f, 0.f};

  int r0 = mbase + lr;      if (r0 > NN - 1) r0 = NN - 1;
  int r1 = mbase + 16 + lr; if (r1 > NN - 1) r1 = NN - 1;

#pragma unroll
  for (int kt = 0; kt < 8; ++kt) {
    const __hip_bfloat16* base = (kt < 4) ? A : X;
    const size_t koff = (size_t)(kt & 3) * 32 + quad * 8;
    short8 a0 = __builtin_nontemporal_load((const short8*)(base + (size_t)r0 * H + koff));
    short8 a1 = __builtin_nontemporal_load((const short8*)(base + (size_t)r1 * H + koff));
    const __hip_bfloat16* wb = Wf + (size_t)kt * 4096 + (size_t)lr * 32 + quad * 8;
#pragma unroll
    for (int ct = 0; ct < 8; ++ct) {
      short8 b = *(const short8*)(wb + ct * 16 * 32);
      acc[0][ct] = __builtin_amdgcn_mfma_f32_16x16x32_bf16(a0, b, acc[0][ct], 0, 0, 0);
      acc[1][ct] = __builtin_amdgcn_mfma_f32_16x16x32_bf16(a1, b, acc[1][ct], 0, 0, 0);
    }
  }

  // C/D layout: col = lane&15, row = quad*4 + reg  [m89-verified]
#pragma unroll
  for (int rt = 0; rt < 2; ++rt) {
    int row0 = mbase + rt * 16 + quad * 4;
#pragma unroll
    for (int ct = 0; ct < 8; ++ct) {
      int n = ct * 16 + lr;
      float bias = br[n];
#pragma unroll
      for (int rg = 0; rg < 4; ++rg) {
        int row = row0 + rg;
        if (row < NN) {
          float v = fmaxf(acc[rt][ct][rg] + bias, 0.f);
          out[(size_t)row * H + n] = __float2bfloat16(v);
        }
      }
    }
  }
}

// ---------------- pooling + head ----------------
#define POOL_TILE 128
__global__ void k_pool2(const __hip_bfloat16* __restrict__ x, const int* __restrict__ batch,
                        float* __restrict__ gsum) {
  int n0 = blockIdx.x * POOL_TILE;
  int j = threadIdx.x;
  int end = n0 + POOL_TILE;
  if (end > NN) end = NN;
  if (n0 >= NN) return;
  int cur_g = batch[n0];
  float acc = 0.f;
  const unsigned short* xs = (const unsigned short*)x;
  for (int i = n0; i < end; ++i) {
    int g = batch[i];  // wave-uniform load, cache-broadcast
    if (g != cur_g) {
      atomicAdd(&gsum[cur_g * H + j], acc);
      acc = 0.f;
      cur_g = g;
    }
    unsigned u = __builtin_nontemporal_load(xs + (size_t)i * H + j);
    acc += __uint_as_float(u << 16);
  }
  atomicAdd(&gsum[cur_g * H + j], acc);
}

__global__ void k_head2(const float* __restrict__ gsum, const int* __restrict__ batch,
                        const float* __restrict__ W5, const float* __restrict__ b5,
                        const float* __restrict__ W6, const float* __restrict__ b6,
                        const float* __restrict__ W7, const float* __restrict__ b7,
                        const float* __restrict__ W8, const float* __restrict__ b8,
                        const float* __restrict__ Wl, const float* __restrict__ bl,
                        float* __restrict__ out) {
  __shared__ float s0[128], s1[128];
  __shared__ int sb[2];
  const int g = blockIdx.x, j = threadIdx.x;
  if (j < 2) {  // binary search for bounds of graph g (batch sorted)
    int tgt = g + j, lo = 0, hi = NN;
    while (lo < hi) {
      int mid = (lo + hi) >> 1;
      if (batch[mid] < tgt) lo = mid + 1; else hi = mid;
    }
    sb[j] = lo;
  }
  __syncthreads();
  float cnt = (float)(sb[1] - sb[0]);
  s0[j] = gsum[g * 128 + j] / fmaxf(cnt, 1.f);
  __syncthreads();
  const float* Ws[4] = {W5, W6, W7, W8};
  const float* bs[4] = {b5, b6, b7, b8};
  float* cur = s0;
  float* nxt = s1;
  for (int L = 0; L < 4; ++L) {
    const float* W = Ws[L];
    float a = bs[L][j];
    for (int k = 0; k < 128; ++k) a = fmaf(cur[k], W[k * 128 + j], a);
    nxt[j] = fmaxf(a, 0.f);
    __syncthreads();
    float* t = cur; cur = nxt; nxt = t;
  }
  if (j < 2) {
    float a = bl[j];
    for (int k = 0; k < 128; ++k) a = fmaf(cur[k], Wl[k * 2 + j], a);
    out[g * 2 + j] = 1.f / (1.f + __expf(-a));
  }
}

// ---------------- launch ----------------
static inline char* ws_take(char*& p, size_t bytes) {
  char* r = p;
  p += (bytes + 255) & ~(size_t)255;
  return r;
}

extern "C" void kernel_launch(void* const* d_in, const int* in_sizes, int n_in,
                              void* d_out, int out_size, void* d_ws, size_t ws_size,
                              hipStream_t stream) {
  const float* x0 = (const float*)d_in[0];
  const int* ei = (const int*)d_in[1];
  const int* batch = (const int*)d_in[2];
  const float* Wr[4] = {(const float*)d_in[3], (const float*)d_in[6],
                        (const float*)d_in[9], (const float*)d_in[12]};
  const float* brr[4] = {(const float*)d_in[4], (const float*)d_in[7],
                         (const float*)d_in[10], (const float*)d_in[13]};
  const float* Wo[4] = {(const float*)d_in[5], (const float*)d_in[8],
                        (const float*)d_in[11], (const float*)d_in[14]};
  const float* W5 = (const float*)d_in[15];
  const float* b5 = (const float*)d_in[16];
  const float* W6 = (const float*)d_in[17];
  const float* b6 = (const float*)d_in[18];
  const float* W7 = (const float*)d_in[19];
  const float* b7 = (const float*)d_in[20];
  const float* W8 = (const float*)d_in[21];
  const float* b8 = (const float*)d_in[22];
  const float* Wl = (const float*)d_in[23];
  const float* bl = (const float*)d_in[24];
  float* out = (float*)d_out;

  char* p = (char*)d_ws;
  int* fcnt = (int*)ws_take(p, (size_t)NN * 4);
  int* colp = (int*)ws_take(p, (size_t)NN * DMAX * 4);
  __hip_bfloat16* agg = (__hip_bfloat16*)ws_take(p, (size_t)NN * H * 2);
  __hip_bfloat16* bufA = (__hip_bfloat16*)ws_take(p, (size_t)(NN + 1) * H * 2);
  __hip_bfloat16* bufB = (__hip_bfloat16*)ws_take(p, (size_t)(NN + 1) * H * 2);
  float* agg4 = (float*)ws_take(p, (size_t)NN * 4 * 4);
  float* gsum = (float*)ws_take(p, (size_t)NG * H * 4);
  __hip_bfloat16* wfall = (__hip_bfloat16*)ws_take(p, 3 * 32768 * 2);
  int* gbase = (int*)ws_take(p, NB * 4);
  __hip_bfloat16* wf1 = wfall;
  __hip_bfloat16* wf2 = wfall + 32768;
  __hip_bfloat16* wf3 = wfall + 65536;
  // pairs buffer (16 MB) aliases agg (25.6 MB): CSR build finishes before the
  // first aggbf3 write to agg.
  int2* pairs = (int2*)agg;
  (void)ws_size; (void)in_sizes; (void)n_in; (void)out_size;

  k_init_wcvt<<<384 + (NB + NG * H + 128 + 255) / 256, 256, 0, stream>>>(
      gbase, gsum, (unsigned*)(bufA + (size_t)NN * H), (unsigned*)(bufB + (size_t)NN * H),
      Wr[1], Wo[1], Wr[2], Wo[2], Wr[3], Wo[3], wfall);
  k_bucket<<<512, 256, 0, stream>>>(ei, gbase, pairs);
  k_fill2<<<NB, 256, 0, stream>>>(pairs, gbase, fcnt, colp);

  // layer 1 (F_IN=4): aggregate in input space (also writes sentinel pads),
  // then small GEMM -> bf16
  k_agg4b<<<(NN * 4 + 255) / 256, 256, 0, stream>>>(x0, fcnt, colp, agg4);
  k_gemm4<<<NN / 2, 256, 0, stream>>>(agg4, x0, Wr[0], Wo[0], brr[0], bufA);

  // layers 2-4: bf16 gather-agg + MFMA GEMM (split; R12 fusion regressed)
  k_aggbf3<<<6250, 256, 0, stream>>>((const uintx4*)bufA, fcnt, colp, (uintx4*)agg);
  k_gemm_mfma<<<782, 256, 0, stream>>>(agg, bufA, wf1, brr[1], bufB);
  k_aggbf3<<<6250, 256, 0, stream>>>((const uintx4*)bufB, fcnt, colp, (uintx4*)agg);
  k_gemm_mfma<<<782, 256, 0, stream>>>(agg, bufB, wf2, brr[2], bufA);
  k_aggbf3<<<6250, 256, 0, stream>>>((const uintx4*)bufA, fcnt, colp, (uintx4*)agg);
  k_gemm_mfma<<<782, 256, 0, stream>>>(agg, bufA, wf3, brr[3], bufB);

  // mean pool + MLP head + sigmoid
  k_pool2<<<(NN + POOL_TILE - 1) / POOL_TILE, 128, 0, stream>>>(bufB, batch, gsum);
  k_head2<<<NG, 128, 0, stream>>>(gsum, batch, W5, b5, W6, b6, W7, b7, W8, b8, Wl, bl, out);
}